// Round 3
// baseline (730.367 us; speedup 1.0000x reference)
//
#include <hip/hip_runtime.h>
#include <cstdint>

// ChessRelativeTransformer on MI355X (gfx950), bf16 MFMA pipeline.
// B=512 T=64 H=16 DH=64 D=1024 NUM_REL=225 scale=0.125
// R3: 8-phase 256^2 GEMMs with FIXED epilogue vmcnt drain (4->2->0).
//     R2 bug: last K-tile (no staging) left vmcnt(4) a no-op, so P2/P3 read
//     A1/B1 half-tiles before their global_load_lds landed.

typedef unsigned short u16;
typedef unsigned int u32;
typedef __bf16 bf16x8 __attribute__((ext_vector_type(8)));
typedef float f32x4 __attribute__((ext_vector_type(4)));

#define MFMA16(a, b, c) __builtin_amdgcn_mfma_f32_16x16x32_bf16(a, b, c, 0, 0, 0)

__device__ __forceinline__ u16 f2bf(float f) {
  u32 u = __builtin_bit_cast(u32, f);
  u = (u + 0x7FFFu + ((u >> 16) & 1u)) >> 16;
  return (u16)u;
}
__device__ __forceinline__ float bf2f(u16 h) {
  return __builtin_bit_cast(float, ((u32)h) << 16);
}

// async global->LDS, 16B per lane; lds_wave_base must be wave-uniform,
// HW places lane i at base + i*16.
__device__ __forceinline__ void g2l16(const void* g, void* lds_wave_base) {
#if __has_builtin(__builtin_amdgcn_global_load_lds)
  __builtin_amdgcn_global_load_lds(
      (const __attribute__((address_space(1))) u32*)(uintptr_t)g,
      (__attribute__((address_space(3))) u32*)(uintptr_t)lds_wave_base, 16, 0, 0);
#else
  uint4 v = *(const uint4*)g;
  *(uint4*)((char*)lds_wave_base + (threadIdx.x & 63) * 16) = v;
#endif
}

// ---------------- fp32 -> bf16 convert (4 elems/thread) ----------------
__global__ __launch_bounds__(256) void k_cvt(const float* __restrict__ src,
                                             u16* __restrict__ dst, int nq) {
  int i = blockIdx.x * 256 + threadIdx.x;
  if (i >= nq) return;
  float4 v = ((const float4*)src)[i];
  ushort4 o;
  o.x = f2bf(v.x); o.y = f2bf(v.y); o.z = f2bf(v.z); o.w = f2bf(v.w);
  ((ushort4*)dst)[i] = o;
}

// ================= 256x256 8-phase GEMM core =================
// A [M][1024] bf16 row-major, Bm [N][1024] bf16 row-major (C = A * Bm^T).
// 512 threads = 8 waves (2M x 4N). BK=64, double-buffered 128KiB LDS.
// LDS halves: A-half h = tile rows R with ((R>>6)&1)==h, stored at
//   sub = (R&63)|((R>>7)<<6), row stride 128B; B-half by col bit5.
// 16B-slot swizzle: slot = (k/8) ^ (sub&7); staging pre-applies inverse on
//   the global source (rule #21: linear LDS dest, swizzled source+read).
// vmcnt ledger (2 loads per half-tile stage per wave):
//   steady state: enter iter with 4 outstanding (A1,B1 of current tile);
//   P1 +A0' ->6, vmcnt(4) drains A1;  P2 +B0' ->6, vmcnt(4) drains B1;
//   P3 +A1' ->6, no wait;             P4 +B1' ->8, vmcnt(4) drains A0',B0'.
//   epilogue (no staging): P1 vmcnt(2) drains A1; P2 vmcnt(0) drains B1.

__device__ __forceinline__ void stageA(const u16* __restrict__ A, int row0,
                                       int kb, char* lds, int buf, int half,
                                       int tid) {
#pragma unroll
  for (int g = 0; g < 2; g++) {
    int ch = g * 512 + tid;
    int sub = ch >> 3, sl = ch & 7;
    int R = (sub & 63) | (half << 6) | ((sub & 64) << 1);
    int kg = sl ^ (sub & 7);
    g2l16(A + (size_t)(row0 + R) * 1024 + kb + kg * 8,
          lds + (buf * 2 + half) * 16384 + g * 8192 + (tid >> 6) * 1024);
  }
}
__device__ __forceinline__ void stageB(const u16* __restrict__ Bm, int col0,
                                       int kb, char* lds, int buf, int half,
                                       int tid) {
#pragma unroll
  for (int g = 0; g < 2; g++) {
    int ch = g * 512 + tid;
    int sub = ch >> 3, sl = ch & 7;
    int C = (sub & 31) | (half << 5) | ((sub & 0x60) << 1);
    int kg = sl ^ (sub & 7);
    g2l16(Bm + (size_t)(col0 + C) * 1024 + kb + kg * 8,
          lds + 65536 + (buf * 2 + half) * 16384 + g * 8192 + (tid >> 6) * 1024);
  }
}

// One phase: quadrant (MH,NH) of current K-tile; optionally stage one
// half-tile (SMAT 0=A,1=B, half SHALF) of the next K-tile; VM: counted
// vmcnt(VM) BEFORE the trailing barrier (cross-wave publish of landed
// stages); VM=-1 -> no wait.
template <int MH, int NH, int SMAT, int SHALF, int VM>
__device__ __forceinline__ void phase8(const u16* __restrict__ A,
                                       const u16* __restrict__ Bm, int row0,
                                       int col0, int kn, char* lds, int buf,
                                       int sbuf, f32x4 (&acc)[8][4], int wr,
                                       int wc, int l15, int l4, int tid,
                                       bool st) {
  bf16x8 af[4][2], bf[2][2];
#pragma unroll
  for (int m = 0; m < 4; m++) {
    int sub = wr * 64 + m * 16 + l15;
    const char* p = lds + (buf * 2 + MH) * 16384 + sub * 128;
#pragma unroll
    for (int kk = 0; kk < 2; kk++)
      af[m][kk] = *(const bf16x8*)(p + (((kk * 4 + l4) ^ (sub & 7)) << 4));
  }
#pragma unroll
  for (int n = 0; n < 2; n++) {
    int sub = wc * 32 + n * 16 + l15;
    const char* p = lds + 65536 + (buf * 2 + NH) * 16384 + sub * 128;
#pragma unroll
    for (int kk = 0; kk < 2; kk++)
      bf[n][kk] = *(const bf16x8*)(p + (((kk * 4 + l4) ^ (sub & 7)) << 4));
  }
  if (st) {
    if (SMAT == 0)
      stageA(A, row0, kn, lds, sbuf, SHALF, tid);
    else
      stageB(Bm, col0, kn, lds, sbuf, SHALF, tid);
  }
  __builtin_amdgcn_s_barrier();
  asm volatile("s_waitcnt lgkmcnt(0)" ::: "memory");
  __builtin_amdgcn_sched_barrier(0);
  __builtin_amdgcn_s_setprio(1);
#pragma unroll
  for (int m = 0; m < 4; m++)
#pragma unroll
    for (int n = 0; n < 2; n++)
#pragma unroll
      for (int kk = 0; kk < 2; kk++)
        acc[MH * 4 + m][NH * 2 + n] =
            MFMA16(af[m][kk], bf[n][kk], acc[MH * 4 + m][NH * 2 + n]);
  __builtin_amdgcn_s_setprio(0);
  if constexpr (VM == 4) asm volatile("s_waitcnt vmcnt(4)" ::: "memory");
  else if constexpr (VM == 2) asm volatile("s_waitcnt vmcnt(2)" ::: "memory");
  else if constexpr (VM == 0) asm volatile("s_waitcnt vmcnt(0)" ::: "memory");
  __builtin_amdgcn_s_barrier();
}

__device__ __forceinline__ void gemm256_core(const u16* __restrict__ A,
                                             const u16* __restrict__ Bm,
                                             int row0, int col0, char* lds,
                                             f32x4 (&acc)[8][4], int tid) {
  const int lane = tid & 63, w = tid >> 6;
  const int wr = w >> 2, wc = w & 3;
  const int l15 = lane & 15, l4 = lane >> 4;
  // prologue: K-tile 0, halves in first-read order A0,B0,A1,B1
  stageA(A, row0, 0, lds, 0, 0, tid);
  stageB(Bm, col0, 0, lds, 0, 0, tid);
  stageA(A, row0, 0, lds, 0, 1, tid);
  stageB(Bm, col0, 0, lds, 0, 1, tid);
  asm volatile("s_waitcnt vmcnt(4)" ::: "memory");
  __builtin_amdgcn_s_barrier();
  for (int u = 0; u < 15; ++u) {
    int buf = u & 1, sbuf = buf ^ 1;
    int kn = (u + 1) * 64;
    // P1:(A0,B0)+stage A0'  P2:(A1,B0)+stage B0'
    // P3:(A1,B1)+stage A1'  P4:(A0,B1)+stage B1'
    phase8<0, 0, 0, 0, 4>(A, Bm, row0, col0, kn, lds, buf, sbuf, acc, wr, wc,
                          l15, l4, tid, true);
    phase8<1, 0, 1, 0, 4>(A, Bm, row0, col0, kn, lds, buf, sbuf, acc, wr, wc,
                          l15, l4, tid, true);
    phase8<1, 1, 0, 1, -1>(A, Bm, row0, col0, kn, lds, buf, sbuf, acc, wr, wc,
                           l15, l4, tid, true);
    phase8<0, 1, 1, 1, 4>(A, Bm, row0, col0, kn, lds, buf, sbuf, acc, wr, wc,
                          l15, l4, tid, true);
  }
  // epilogue K-tile 15 (buf 1): no staging; drain 4 -> 2 -> 0
  phase8<0, 0, 0, 0, 2>(A, Bm, row0, col0, 0, lds, 1, 0, acc, wr, wc, l15, l4,
                        tid, false);
  phase8<1, 0, 1, 0, 0>(A, Bm, row0, col0, 0, lds, 1, 0, acc, wr, wc, l15, l4,
                        tid, false);
  phase8<1, 1, 0, 1, -1>(A, Bm, row0, col0, 0, lds, 1, 0, acc, wr, wc, l15, l4,
                         tid, false);
  phase8<0, 1, 1, 1, -1>(A, Bm, row0, col0, 0, lds, 1, 0, acc, wr, wc, l15, l4,
                         tid, false);
}

// ---------------- QKV GEMM: [32768x1024] x [3072x1024]^T ----------------
__global__ __launch_bounds__(512, 2) void k_gemm_qkv(
    const u16* __restrict__ A, const u16* __restrict__ Bm,
    const float* __restrict__ bq, const float* __restrict__ bk,
    const float* __restrict__ bv, u16* __restrict__ Qb, u16* __restrict__ Kb,
    u16* __restrict__ Vtb) {
  __shared__ char lds[131072];
  const int tid = threadIdx.x;
  const int lane = tid & 63, w = tid >> 6;
  const int wr = w >> 2, wc = w & 3;
  const int l15 = lane & 15, l4 = lane >> 4;
  // XCD-aware swizzle: 1536 blocks = 8 XCD chunks of 192
  int f = blockIdx.x;
  int swz = (f & 7) * 192 + (f >> 3);
  int brow = swz % 128, bcol = swz / 128;
  const int row0 = brow * 256, col0 = bcol * 256;
  f32x4 acc[8][4] = {};
  gemm256_core(A, Bm, row0, col0, lds, acc, tid);
#pragma unroll
  for (int nf = 0; nf < 4; nf++) {
    int col = col0 + wc * 64 + nf * 16 + l15;
    int sel = col >> 10, hd = col & 1023;
    int h = hd >> 6, d = hd & 63;
    const float* bp = (sel == 0) ? bq : (sel == 1) ? bk : bv;
    float bias = bp[hd];
    u16* dst = (sel == 0) ? Qb : (sel == 1) ? Kb : Vtb;
#pragma unroll
    for (int mf = 0; mf < 8; mf++) {
      int rowb = row0 + wr * 128 + mf * 16 + l4 * 4;
#pragma unroll
      for (int j = 0; j < 4; j++) {
        int row = rowb + j;
        int b = row >> 6, t = row & 63;
        size_t off = (sel == 2)
                         ? ((size_t)(b * 16 + h)) * 4096 + d * 64 + t
                         : ((size_t)(b * 16 + h)) * 4096 + t * 64 + d;
        dst[off] = f2bf(acc[mf][nf][j] + bias);
      }
    }
  }
}

// ---------------- output GEMM: [32768x1024] x [1024x1024]^T + bias -> fp32 --
__global__ __launch_bounds__(512, 2) void k_gemm_out(
    const u16* __restrict__ A, const u16* __restrict__ Bm,
    const float* __restrict__ bo, float* __restrict__ out) {
  __shared__ char lds[131072];
  const int tid = threadIdx.x;
  const int lane = tid & 63, w = tid >> 6;
  const int wr = w >> 2, wc = w & 3;
  const int l15 = lane & 15, l4 = lane >> 4;
  int f = blockIdx.x;  // 512 blocks = 8 chunks of 64
  int swz = (f & 7) * 64 + (f >> 3);
  int brow = swz & 127, bcol = swz >> 7;
  const int row0 = brow * 256, col0 = bcol * 256;
  f32x4 acc[8][4] = {};
  gemm256_core(A, Bm, row0, col0, lds, acc, tid);
#pragma unroll
  for (int nf = 0; nf < 4; nf++) {
    int col = col0 + wc * 64 + nf * 16 + l15;
    float bias = bo[col];
#pragma unroll
    for (int mf = 0; mf < 8; mf++) {
      int rowb = row0 + wr * 128 + mf * 16 + l4 * 4;
#pragma unroll
      for (int j = 0; j < 4; j++)
        out[(size_t)(rowb + j) * 1024 + col] = acc[mf][nf][j] + bias;
    }
  }
}

// ---------------- bias1[b,h,t,s] = sum_d q[b,h,t,d]*rel_k[h,idx[t,s],d] + T3[h,t,s]
// grid (t=64, h=16, bc=2); per block: (256 b-rows) x 64 s, K=64
__global__ __launch_bounds__(256) void k_bias1(
    const u16* __restrict__ Qb, const u16* __restrict__ relq,
    const u16* __restrict__ relk, const int* __restrict__ relidx,
    u16* __restrict__ bias1) {
  const int tid = threadIdx.x, lane = tid & 63, w = tid >> 6;
  const int l15 = lane & 15, l4 = lane >> 4;
  const int t = blockIdx.x, h = blockIdx.y, bc = blockIdx.z;
  __shared__ char lds[16640];
  char* RK = lds;
  char* RQ = lds + 8192;
  float* T3 = (float*)(lds + 16384);
#pragma unroll
  for (int c = 0; c < 2; c++) {
    int ch = c * 256 + tid;
    int sr = ch >> 3, sl = (ch & 7) ^ (sr & 7);
    int ri = relidx[t * 64 + sr];
    size_t so = ((size_t)h * 225 + ri) * 64 + sl * 8;
    g2l16(relk + so, RK + c * 4096 + w * 1024);
    g2l16(relq + so, RQ + c * 4096 + w * 1024);
  }
  __syncthreads();
  if (tid < 64) {
    int sr = tid;
    float sum = 0.f;
#pragma unroll
    for (int sl = 0; sl < 8; sl++) {
      int o = sr * 128 + ((sl ^ (sr & 7)) << 4);
      bf16x8 aq = *(const bf16x8*)(RQ + o);
      bf16x8 ak = *(const bf16x8*)(RK + o);
#pragma unroll
      for (int j = 0; j < 8; j++) sum += (float)aq[j] * (float)ak[j];
    }
    T3[sr] = sum;
  }
  bf16x8 bfr[4][2];
#pragma unroll
  for (int n = 0; n < 4; n++)
#pragma unroll
    for (int kh = 0; kh < 2; kh++) {
      int r = n * 16 + l15;
      int sl = ((kh << 2) + l4) ^ (r & 7);
      bfr[n][kh] = *(const bf16x8*)(RK + r * 128 + sl * 16);
    }
  __syncthreads();
  f32x4 acc[4][4] = {};
#pragma unroll
  for (int m = 0; m < 4; m++) {
    int bb = bc * 256 + w * 64 + m * 16 + l15;
    const u16* ap = Qb + ((size_t)(bb * 16 + h)) * 4096 + t * 64 + l4 * 8;
    bf16x8 a0 = *(const bf16x8*)ap;
    bf16x8 a1 = *(const bf16x8*)(ap + 32);
#pragma unroll
    for (int n = 0; n < 4; n++) {
      acc[m][n] = MFMA16(a0, bfr[n][0], acc[m][n]);
      acc[m][n] = MFMA16(a1, bfr[n][1], acc[m][n]);
    }
  }
#pragma unroll
  for (int m = 0; m < 4; m++)
#pragma unroll
    for (int n = 0; n < 4; n++)
#pragma unroll
      for (int j = 0; j < 4; j++) {
        int bb = bc * 256 + w * 64 + m * 16 + l4 * 4 + j;
        int s_ = n * 16 + l15;
        bias1[((size_t)(bb * 16 + h)) * 4096 + t * 64 + s_] =
            f2bf(acc[m][n][j] + T3[s_]);
      }
}

// ---------------- bias2[b,h,s,t] = sum_d rel_q[h,idx[t,s],d]*k[b,h,s,d]
// grid (s=64, h=16, bc=2)
__global__ __launch_bounds__(256) void k_bias2(
    const u16* __restrict__ Kb, const u16* __restrict__ relq,
    const int* __restrict__ relidx, u16* __restrict__ bias2) {
  const int tid = threadIdx.x, lane = tid & 63, w = tid >> 6;
  const int l15 = lane & 15, l4 = lane >> 4;
  const int s = blockIdx.x, h = blockIdx.y, bc = blockIdx.z;
  __shared__ char lds[8192];
#pragma unroll
  for (int c = 0; c < 2; c++) {
    int ch = c * 256 + tid;
    int tq = ch >> 3, sl = (ch & 7) ^ (tq & 7);
    int ri = relidx[tq * 64 + s];
    g2l16(relq + ((size_t)h * 225 + ri) * 64 + sl * 8,
          lds + c * 4096 + w * 1024);
  }
  __syncthreads();
  bf16x8 bfr[4][2];
#pragma unroll
  for (int n = 0; n < 4; n++)
#pragma unroll
    for (int kh = 0; kh < 2; kh++) {
      int r = n * 16 + l15;
      int sl = ((kh << 2) + l4) ^ (r & 7);
      bfr[n][kh] = *(const bf16x8*)(lds + r * 128 + sl * 16);
    }
  f32x4 acc[4][4] = {};
#pragma unroll
  for (int m = 0; m < 4; m++) {
    int bb = bc * 256 + w * 64 + m * 16 + l15;
    const u16* ap = Kb + ((size_t)(bb * 16 + h)) * 4096 + s * 64 + l4 * 8;
    bf16x8 a0 = *(const bf16x8*)ap;
    bf16x8 a1 = *(const bf16x8*)(ap + 32);
#pragma unroll
    for (int n = 0; n < 4; n++) {
      acc[m][n] = MFMA16(a0, bfr[n][0], acc[m][n]);
      acc[m][n] = MFMA16(a1, bfr[n][1], acc[m][n]);
    }
  }
#pragma unroll
  for (int m = 0; m < 4; m++)
#pragma unroll
    for (int n = 0; n < 4; n++)
#pragma unroll
      for (int j = 0; j < 4; j++) {
        int bb = bc * 256 + w * 64 + m * 16 + l4 * 4 + j;
        int tcol = n * 16 + l15;
        bias2[((size_t)(bb * 16 + h)) * 4096 + s * 64 + tcol] =
            f2bf(acc[m][n][j]);
      }
}

// ---------------- attention per (b,h): S=QK^T + b1 + b2^T, softmax, P, PV ----
__global__ __launch_bounds__(256) void k_attn(
    const u16* __restrict__ Qb, const u16* __restrict__ Kb,
    const u16* __restrict__ Vtb, const u16* __restrict__ b1g,
    const u16* __restrict__ b2g, u16* __restrict__ Pg,
    u16* __restrict__ aout) {
  const int tid = threadIdx.x, lane = tid & 63, w = tid >> 6;
  const int l15 = lane & 15, l4 = lane >> 4;
  const int b = blockIdx.x, h = blockIdx.y;
  __shared__ char lds[49152];
  char* Qt = lds;
  char* Kt = lds + 8192;
  char* Vt = lds + 16384;
  char* B1 = lds + 24576;
  char* B2 = lds + 32768;
  char* Pt = lds + 40960;
  const size_t base = ((size_t)(b * 16 + h)) * 4096;
#pragma unroll
  for (int c = 0; c < 2; c++) {
    int ch = c * 256 + tid;
    int r = ch >> 3, sl = (ch & 7) ^ (r & 7);
    size_t so = base + r * 64 + sl * 8;
    int dst = c * 4096 + w * 1024;
    g2l16(Qb + so, Qt + dst);
    g2l16(Kb + so, Kt + dst);
    g2l16(Vtb + so, Vt + dst);
    g2l16(b1g + so, B1 + dst);
    g2l16(b2g + so, B2 + dst);
  }
  __syncthreads();
  // S = Q K^T, wave w owns rows [w*16, w*16+16)
  f32x4 acc[4] = {};
  bf16x8 qf[2];
  {
    int r = w * 16 + l15;
#pragma unroll
    for (int kh = 0; kh < 2; kh++) {
      int sl = ((kh << 2) + l4) ^ (r & 7);
      qf[kh] = *(const bf16x8*)(Qt + r * 128 + sl * 16);
    }
  }
#pragma unroll
  for (int n = 0; n < 4; n++) {
    int r = n * 16 + l15;
#pragma unroll
    for (int kh = 0; kh < 2; kh++) {
      int sl = ((kh << 2) + l4) ^ (r & 7);
      bf16x8 kf = *(const bf16x8*)(Kt + r * 128 + sl * 16);
      acc[n] = MFMA16(qf[kh], kf, acc[n]);
    }
  }
  const int t0 = w * 16 + l4 * 4;
#pragma unroll
  for (int j = 0; j < 4; j++) {
    int t_ = t0 + j;
    float lv[4];
#pragma unroll
    for (int n = 0; n < 4; n++) {
      int s_ = n * 16 + l15;
      float x = acc[n][j];
      x += bf2f(*(const u16*)(B1 + t_ * 128 + ((s_ * 2) ^ ((t_ & 7) << 4))));
      x += bf2f(*(const u16*)(B2 + s_ * 128 + ((t_ * 2) ^ ((s_ & 7) << 4))));
      lv[n] = x * 0.125f;
    }
    float mx = fmaxf(fmaxf(lv[0], lv[1]), fmaxf(lv[2], lv[3]));
#pragma unroll
    for (int d = 1; d < 16; d <<= 1) mx = fmaxf(mx, __shfl_xor(mx, d, 64));
    float e0 = __expf(lv[0] - mx), e1 = __expf(lv[1] - mx);
    float e2 = __expf(lv[2] - mx), e3 = __expf(lv[3] - mx);
    float sum = e0 + e1 + e2 + e3;
#pragma unroll
    for (int d = 1; d < 16; d <<= 1) sum += __shfl_xor(sum, d, 64);
    float inv = 1.0f / sum;
    float pe[4] = {e0 * inv, e1 * inv, e2 * inv, e3 * inv};
#pragma unroll
    for (int n = 0; n < 4; n++) {
      int s_ = n * 16 + l15;
      *(u16*)(Pt + t_ * 128 + ((s_ * 2) ^ ((t_ & 7) << 4))) = f2bf(pe[n]);
    }
  }
  __syncthreads();
  // P -> global (linearized, undo swizzle)
#pragma unroll
  for (int c = 0; c < 2; c++) {
    int ch = c * 256 + tid;
    int r = ch >> 3, sl = ch & 7;
    uint4 v = *(const uint4*)(Pt + r * 128 + ((sl ^ (r & 7)) << 4));
    *((uint4*)(Pg + base) + ch) = v;
  }
  // out_v = P * V  (V staged transposed: Vt[d][t])
  f32x4 acc2[4] = {};
  bf16x8 pf[2];
  {
    int r = w * 16 + l15;
#pragma unroll
    for (int kh = 0; kh < 2; kh++) {
      int sl = ((kh << 2) + l4) ^ (r & 7);
      pf[kh] = *(const bf16x8*)(Pt + r * 128 + sl * 16);
    }
  }
#pragma unroll
  for (int n = 0; n < 4; n++) {
    int r = n * 16 + l15;  // d row
#pragma unroll
    for (int kh = 0; kh < 2; kh++) {
      int sl = ((kh << 2) + l4) ^ (r & 7);
      bf16x8 vf = *(const bf16x8*)(Vt + r * 128 + sl * 16);
      acc2[n] = MFMA16(pf[kh], vf, acc2[n]);
    }
  }
#pragma unroll
  for (int n = 0; n < 4; n++)
#pragma unroll
    for (int j = 0; j < 4; j++) {
      int t_ = t0 + j, d_ = n * 16 + l15;
      aout[((size_t)(b * 64 + t_)) * 1024 + h * 64 + d_] = f2bf(acc2[n][j]);
    }
}

// ---------------- out_relv: per (h,t): aout[b,t,h,d] += sum_s P[b,s]*rel_v[h,idx[t,s],d]
__global__ __launch_bounds__(256) void k_relv(
    const u16* __restrict__ Pg, const u16* __restrict__ relv,
    const int* __restrict__ relidx, u16* __restrict__ aout) {
  const int tid = threadIdx.x, lane = tid & 63, w = tid >> 6;
  const int l15 = lane & 15, l4 = lane >> 4;
  const int t = blockIdx.x, h = blockIdx.y, bc = blockIdx.z;
  __shared__ char lds[8192];
#pragma unroll
  for (int c = 0; c < 2; c++) {
    int ch = c * 256 + tid;
    int sr = ch >> 3, sl = (ch & 7) ^ (sr & 7);
    int ri = relidx[t * 64 + sr];
    g2l16(relv + ((size_t)h * 225 + ri) * 64 + sl * 8,
          lds + c * 4096 + w * 1024);
  }
  __syncthreads();
  bf16x8 bfr[4][2];
#pragma unroll
  for (int n = 0; n < 4; n++)
#pragma unroll
    for (int kh = 0; kh < 2; kh++) {
      bf16x8 tmp;
#pragma unroll
      for (int j = 0; j < 8; j++) {
        int s_ = (kh << 5) + (l4 << 3) + j;
        int d_ = n * 16 + l15;
        u16 u = *(const u16*)(lds + s_ * 128 + ((d_ * 2) ^ ((s_ & 7) << 4)));
        tmp[j] = __builtin_bit_cast(__bf16, u);
      }
      bfr[n][kh] = tmp;
    }
  f32x4 acc[4][4] = {};
#pragma unroll
  for (int m = 0; m < 4; m++) {
    int bb = bc * 256 + w * 64 + m * 16 + l15;
    const u16* ap = Pg + ((size_t)(bb * 16 + h)) * 4096 + t * 64 + l4 * 8;
    bf16x8 a0 = *(const bf16x8*)ap;
    bf16x8 a1 = *(const bf16x8*)(ap + 32);
#pragma unroll
    for (int n = 0; n < 4; n++) {
      acc[m][n] = MFMA16(a0, bfr[n][0], acc[m][n]);
      acc[m][n] = MFMA16(a1, bfr[n][1], acc[m][n]);
    }
  }
#pragma unroll
  for (int m = 0; m < 4; m++)
#pragma unroll
    for (int n = 0; n < 4; n++)
#pragma unroll
      for (int j = 0; j < 4; j++) {
        int bb = bc * 256 + w * 64 + m * 16 + l4 * 4 + j;
        int d_ = n * 16 + l15;
        size_t o = ((size_t)(bb * 64 + t)) * 1024 + h * 64 + d_;
        aout[o] = f2bf(bf2f(aout[o]) + acc[m][n][j]);
      }
}

extern "C" void kernel_launch(void* const* d_in, const int* in_sizes, int n_in,
                              void* d_out, int out_size, void* d_ws,
                              size_t ws_size, hipStream_t stream) {
  const float* x = (const float*)d_in[0];
  const float* Wq = (const float*)d_in[1];
  const float* bq = (const float*)d_in[2];
  const float* Wk = (const float*)d_in[3];
  const float* bk = (const float*)d_in[4];
  const float* Wv = (const float*)d_in[5];
  const float* bv = (const float*)d_in[6];
  const float* Wo = (const float*)d_in[7];
  const float* bo = (const float*)d_in[8];
  const float* rq = (const float*)d_in[9];
  const float* rk = (const float*)d_in[10];
  const float* rv = (const float*)d_in[11];
  const int* ridx = (const int*)d_in[12];
  float* out = (float*)d_out;

  char* ws = (char*)d_ws;
  const size_t MB = 1ull << 20;
  u16* xb = (u16*)(ws + 0);  // reused as P after k_gemm_qkv consumes it
  u16* Qb = (u16*)(ws + 64 * MB);
  u16* Kb = (u16*)(ws + 128 * MB);
  u16* Vtb = (u16*)(ws + 192 * MB);
  u16* b1 = (u16*)(ws + 256 * MB);
  u16* b2 = (u16*)(ws + 320 * MB);
  u16* aout = (u16*)(ws + 384 * MB);
  u16* wqkv = (u16*)(ws + 448 * MB);
  u16* wo = (u16*)(ws + 454 * MB);
  u16* relq = (u16*)(ws + 456 * MB);
  u16* relk = (u16*)(ws + 457 * MB);
  u16* relv = (u16*)(ws + 458 * MB);
  u16* Pg = xb;

  k_cvt<<<32768, 256, 0, stream>>>(x, xb, 8388608);
  k_cvt<<<1024, 256, 0, stream>>>(Wq, wqkv, 262144);
  k_cvt<<<1024, 256, 0, stream>>>(Wk, wqkv + 1048576, 262144);
  k_cvt<<<1024, 256, 0, stream>>>(Wv, wqkv + 2097152, 262144);
  k_cvt<<<1024, 256, 0, stream>>>(Wo, wo, 262144);
  k_cvt<<<225, 256, 0, stream>>>(rq, relq, 57600);
  k_cvt<<<225, 256, 0, stream>>>(rk, relk, 57600);
  k_cvt<<<225, 256, 0, stream>>>(rv, relv, 57600);

  k_gemm_qkv<<<1536, 512, 0, stream>>>(xb, wqkv, bq, bk, bv, Qb, Kb, Vtb);
  k_bias1<<<dim3(64, 16, 2), 256, 0, stream>>>(Qb, relq, relk, ridx, b1);
  k_bias2<<<dim3(64, 16, 2), 256, 0, stream>>>(Kb, relq, ridx, b2);
  k_attn<<<dim3(512, 16), 256, 0, stream>>>(Qb, Kb, Vtb, b1, b2, Pg, aout);
  k_relv<<<dim3(64, 16, 2), 256, 0, stream>>>(Pg, relv, ridx, aout);
  k_gemm_out<<<512, 512, 0, stream>>>(aout, wo, bo, out);
}

// Round 4
// 623.883 us; speedup vs baseline: 1.1707x; 1.1707x over previous
//
#include <hip/hip_runtime.h>
#include <cstdint>

// ChessRelativeTransformer on MI355X (gfx950), bf16 MFMA pipeline.
// B=512 T=64 H=16 DH=64 D=1024 NUM_REL=225 scale=0.125
// R4: 8-phase core reworked: register-cached fragments (24 ds_read_b128 per
//     K-tile per wave, was 48), 2 K-tiles/iteration with vmcnt(4) only at
//     P4/P8 (was 3 waits/tile), V stored natural [b,h,t,d] (coalesced
//     writes; PV uses scalar column gather like k_relv), col-fastest XCD
//     ordering for A-reuse in L2/L3.

typedef unsigned short u16;
typedef unsigned int u32;
typedef __bf16 bf16x8 __attribute__((ext_vector_type(8)));
typedef float f32x4 __attribute__((ext_vector_type(4)));

#define MFMA16(a, b, c) __builtin_amdgcn_mfma_f32_16x16x32_bf16(a, b, c, 0, 0, 0)

__device__ __forceinline__ u16 f2bf(float f) {
  u32 u = __builtin_bit_cast(u32, f);
  u = (u + 0x7FFFu + ((u >> 16) & 1u)) >> 16;
  return (u16)u;
}
__device__ __forceinline__ float bf2f(u16 h) {
  return __builtin_bit_cast(float, ((u32)h) << 16);
}

__device__ __forceinline__ void g2l16(const void* g, void* lds_wave_base) {
#if __has_builtin(__builtin_amdgcn_global_load_lds)
  __builtin_amdgcn_global_load_lds(
      (const __attribute__((address_space(1))) u32*)(uintptr_t)g,
      (__attribute__((address_space(3))) u32*)(uintptr_t)lds_wave_base, 16, 0, 0);
#else
  uint4 v = *(const uint4*)g;
  *(uint4*)((char*)lds_wave_base + (threadIdx.x & 63) * 16) = v;
#endif
}

// ---------------- fp32 -> bf16 convert (4 elems/thread) ----------------
__global__ __launch_bounds__(256) void k_cvt(const float* __restrict__ src,
                                             u16* __restrict__ dst, int nq) {
  int i = blockIdx.x * 256 + threadIdx.x;
  if (i >= nq) return;
  float4 v = ((const float4*)src)[i];
  ushort4 o;
  o.x = f2bf(v.x); o.y = f2bf(v.y); o.z = f2bf(v.z); o.w = f2bf(v.w);
  ((ushort4*)dst)[i] = o;
}

// ================= 256x256 8-phase GEMM core (R4) =================
// C = A * Bm^T. 512 thr = 8 waves (2M x 4N), BK=64, 128KiB dbuf LDS.
// A-half h = rows with bit6==h at sub=(R&63)|((R>>7)<<6); B-half by col
// bit5. Slot swizzle slot=(k/8)^(sub&7), inverse pre-applied on global src.
// Phases per iteration (2 K-tiles: even e in buf0, odd o in buf1):
//  P1 (e,q00): read A0->afA,B0->bfB | stage buf1.B1[o]
//  P2 (e,q10): read A1->afC         | stage buf1.A0[o]
//  P3 (e,q11): read B1->bfB         | stage buf0.B0[e+2]
//  P4 (e,q01): no reads             | stage buf0.A1[e+2] | vmcnt(4)
//  P5-P8: same on buf1/tile o, staging buf0.A0/B1[e+2], buf1.B0/A1[o+2],
//  vmcnt(4) at P8. Ledger: every wait leaves exactly the 2 newest stages
//  (4 loads) in flight; every staged half lands >=1 vmcnt+barrier before
//  its first read. Peeled last iter: stages P1/P2 only, vmcnt(0) at P4.

__device__ __forceinline__ void stageA(const u16* __restrict__ A, int row0,
                                       int kb, char* lds, int buf, int half,
                                       int tid) {
#pragma unroll
  for (int g = 0; g < 2; g++) {
    int ch = g * 512 + tid;
    int sub = ch >> 3, sl = ch & 7;
    int R = (sub & 63) | (half << 6) | ((sub & 64) << 1);
    int kg = sl ^ (sub & 7);
    g2l16(A + (size_t)(row0 + R) * 1024 + kb + kg * 8,
          lds + (buf * 2 + half) * 16384 + g * 8192 + (tid >> 6) * 1024);
  }
}
__device__ __forceinline__ void stageB(const u16* __restrict__ Bm, int col0,
                                       int kb, char* lds, int buf, int half,
                                       int tid) {
#pragma unroll
  for (int g = 0; g < 2; g++) {
    int ch = g * 512 + tid;
    int sub = ch >> 3, sl = ch & 7;
    int C = (sub & 31) | (half << 5) | ((sub & 0x60) << 1);
    int kg = sl ^ (sub & 7);
    g2l16(Bm + (size_t)(col0 + C) * 1024 + kb + kg * 8,
          lds + 65536 + (buf * 2 + half) * 16384 + g * 8192 + (tid >> 6) * 1024);
  }
}

// RA: 0 none, 1 -> afA, 2 -> afC.  RB: 0 none, 1 -> bfB.  USEA: 0 afA, 1 afC.
// SMAT: 0 stage A, 1 stage B. VMn: -1 none, else vmcnt value.
template <int MH, int NH, int RA, int RB, int USEA, int SMAT, int SHALF,
          int SBUF, int KADD, int VMn>
__device__ __forceinline__ void phz(const u16* __restrict__ A,
                                    const u16* __restrict__ Bm, int row0,
                                    int col0, int k0, char* lds, int cbuf,
                                    f32x4 (&acc)[8][4], bf16x8 (&afA)[4][2],
                                    bf16x8 (&afC)[4][2], bf16x8 (&bfB)[2][2],
                                    int wr, int wc, int l15, int l4, int tid,
                                    bool st) {
  if (RA) {
#pragma unroll
    for (int m = 0; m < 4; m++) {
      int sub = wr * 64 + m * 16 + l15;
      const char* p = lds + (cbuf * 2 + MH) * 16384 + sub * 128;
#pragma unroll
      for (int kk = 0; kk < 2; kk++) {
        bf16x8 v = *(const bf16x8*)(p + (((kk * 4 + l4) ^ (sub & 7)) << 4));
        if (RA == 1) afA[m][kk] = v; else afC[m][kk] = v;
      }
    }
  }
  if (RB) {
#pragma unroll
    for (int n = 0; n < 2; n++) {
      int sub = wc * 32 + n * 16 + l15;
      const char* p = lds + 65536 + (cbuf * 2 + NH) * 16384 + sub * 128;
#pragma unroll
      for (int kk = 0; kk < 2; kk++)
        bfB[n][kk] = *(const bf16x8*)(p + (((kk * 4 + l4) ^ (sub & 7)) << 4));
    }
  }
  if (st) {
    if (SMAT == 0)
      stageA(A, row0, k0 + KADD * 64, lds, SBUF, SHALF, tid);
    else
      stageB(Bm, col0, k0 + KADD * 64, lds, SBUF, SHALF, tid);
  }
  __builtin_amdgcn_s_barrier();
  asm volatile("s_waitcnt lgkmcnt(0)" ::: "memory");
  __builtin_amdgcn_sched_barrier(0);
  __builtin_amdgcn_s_setprio(1);
#pragma unroll
  for (int m = 0; m < 4; m++)
#pragma unroll
    for (int n = 0; n < 2; n++)
#pragma unroll
      for (int kk = 0; kk < 2; kk++)
        acc[MH * 4 + m][NH * 2 + n] = MFMA16(USEA ? afC[m][kk] : afA[m][kk],
                                             bfB[n][kk],
                                             acc[MH * 4 + m][NH * 2 + n]);
  __builtin_amdgcn_s_setprio(0);
  if constexpr (VMn == 4) asm volatile("s_waitcnt vmcnt(4)" ::: "memory");
  else if constexpr (VMn == 0) asm volatile("s_waitcnt vmcnt(0)" ::: "memory");
  __builtin_amdgcn_s_barrier();
}

__device__ __forceinline__ void gemm256_core(const u16* __restrict__ A,
                                             const u16* __restrict__ Bm,
                                             int row0, int col0, char* lds,
                                             f32x4 (&acc)[8][4], int tid) {
  const int lane = tid & 63, w = tid >> 6;
  const int wr = w >> 2, wc = w & 3;
  const int l15 = lane & 15, l4 = lane >> 4;
  bf16x8 afA[4][2], afC[4][2], bfB[2][2];
  // prologue: tile0 all 4 halves (buf0) + tile1 B0,A1 (buf1); drain buf0.
  stageA(A, row0, 0, lds, 0, 0, tid);
  stageB(Bm, col0, 0, lds, 0, 0, tid);
  stageA(A, row0, 0, lds, 0, 1, tid);
  stageB(Bm, col0, 0, lds, 0, 1, tid);
  stageB(Bm, col0, 64, lds, 1, 0, tid);
  stageA(A, row0, 64, lds, 1, 1, tid);
  asm volatile("s_waitcnt vmcnt(4)" ::: "memory");
  __builtin_amdgcn_s_barrier();
  for (int u = 0; u < 7; ++u) {
    int k0 = u * 128;
    phz<0,0,1,1,0, 1,1,1,1,-1>(A,Bm,row0,col0,k0,lds,0,acc,afA,afC,bfB,wr,wc,l15,l4,tid,true);
    phz<1,0,2,0,1, 0,0,1,1,-1>(A,Bm,row0,col0,k0,lds,0,acc,afA,afC,bfB,wr,wc,l15,l4,tid,true);
    phz<1,1,0,1,1, 1,0,0,2,-1>(A,Bm,row0,col0,k0,lds,0,acc,afA,afC,bfB,wr,wc,l15,l4,tid,true);
    phz<0,1,0,0,0, 0,1,0,2, 4>(A,Bm,row0,col0,k0,lds,0,acc,afA,afC,bfB,wr,wc,l15,l4,tid,true);
    phz<0,0,1,1,0, 0,0,0,2,-1>(A,Bm,row0,col0,k0,lds,1,acc,afA,afC,bfB,wr,wc,l15,l4,tid,true);
    phz<1,0,2,0,1, 1,1,0,2,-1>(A,Bm,row0,col0,k0,lds,1,acc,afA,afC,bfB,wr,wc,l15,l4,tid,true);
    phz<1,1,0,1,1, 1,0,1,3,-1>(A,Bm,row0,col0,k0,lds,1,acc,afA,afC,bfB,wr,wc,l15,l4,tid,true);
    phz<0,1,0,0,0, 0,1,1,3, 4>(A,Bm,row0,col0,k0,lds,1,acc,afA,afC,bfB,wr,wc,l15,l4,tid,true);
  }
  {  // peeled final iteration (tiles 14,15): stage only tile15.B1/A0
    const int k0 = 896;
    phz<0,0,1,1,0, 1,1,1,1,-1>(A,Bm,row0,col0,k0,lds,0,acc,afA,afC,bfB,wr,wc,l15,l4,tid,true);
    phz<1,0,2,0,1, 0,0,1,1,-1>(A,Bm,row0,col0,k0,lds,0,acc,afA,afC,bfB,wr,wc,l15,l4,tid,true);
    phz<1,1,0,1,1, 0,0,0,0,-1>(A,Bm,row0,col0,k0,lds,0,acc,afA,afC,bfB,wr,wc,l15,l4,tid,false);
    phz<0,1,0,0,0, 0,0,0,0, 0>(A,Bm,row0,col0,k0,lds,0,acc,afA,afC,bfB,wr,wc,l15,l4,tid,false);
    phz<0,0,1,1,0, 0,0,0,0,-1>(A,Bm,row0,col0,k0,lds,1,acc,afA,afC,bfB,wr,wc,l15,l4,tid,false);
    phz<1,0,2,0,1, 0,0,0,0,-1>(A,Bm,row0,col0,k0,lds,1,acc,afA,afC,bfB,wr,wc,l15,l4,tid,false);
    phz<1,1,0,1,1, 0,0,0,0,-1>(A,Bm,row0,col0,k0,lds,1,acc,afA,afC,bfB,wr,wc,l15,l4,tid,false);
    phz<0,1,0,0,0, 0,0,0,0,-1>(A,Bm,row0,col0,k0,lds,1,acc,afA,afC,bfB,wr,wc,l15,l4,tid,false);
  }
}

// ---------------- QKV GEMM: [32768x1024] x [3072x1024]^T ----------------
__global__ __launch_bounds__(512, 2) void k_gemm_qkv(
    const u16* __restrict__ A, const u16* __restrict__ Bm,
    const float* __restrict__ bq, const float* __restrict__ bk,
    const float* __restrict__ bv, u16* __restrict__ Qb, u16* __restrict__ Kb,
    u16* __restrict__ Vb) {
  __shared__ char lds[131072];
  const int tid = threadIdx.x;
  const int lane = tid & 63, w = tid >> 6;
  const int wr = w >> 2, wc = w & 3;
  const int l15 = lane & 15, l4 = lane >> 4;
  // XCD chunks of 192, col-fastest within: A-slab reused 12x consecutively
  int f = blockIdx.x;
  int swz = (f & 7) * 192 + (f >> 3);
  int bcol = swz % 12, brow = swz / 12;
  const int row0 = brow * 256, col0 = bcol * 256;
  f32x4 acc[8][4] = {};
  gemm256_core(A, Bm, row0, col0, lds, acc, tid);
#pragma unroll
  for (int nf = 0; nf < 4; nf++) {
    int col = col0 + wc * 64 + nf * 16 + l15;
    int sel = col >> 10, hd = col & 1023;
    int h = hd >> 6, d = hd & 63;
    const float* bp = (sel == 0) ? bq : (sel == 1) ? bk : bv;
    float bias = bp[hd];
    u16* dst = (sel == 0) ? Qb : (sel == 1) ? Kb : Vb;
#pragma unroll
    for (int mf = 0; mf < 8; mf++) {
      int rowb = row0 + wr * 128 + mf * 16 + l4 * 4;
#pragma unroll
      for (int j = 0; j < 4; j++) {
        int row = rowb + j;
        int b = row >> 6, t = row & 63;
        dst[((size_t)(b * 16 + h)) * 4096 + t * 64 + d] =
            f2bf(acc[mf][nf][j] + bias);
      }
    }
  }
}

// ---------------- output GEMM: [32768x1024] x [1024x1024]^T + bias -> fp32 --
__global__ __launch_bounds__(512, 2) void k_gemm_out(
    const u16* __restrict__ A, const u16* __restrict__ Bm,
    const float* __restrict__ bo, float* __restrict__ out) {
  __shared__ char lds[131072];
  const int tid = threadIdx.x;
  const int lane = tid & 63, w = tid >> 6;
  const int wr = w >> 2, wc = w & 3;
  const int l15 = lane & 15, l4 = lane >> 4;
  int f = blockIdx.x;  // 512 blocks = 8 chunks of 64, col-fastest
  int swz = (f & 7) * 64 + (f >> 3);
  int bcol = swz & 3, brow = swz >> 2;
  const int row0 = brow * 256, col0 = bcol * 256;
  f32x4 acc[8][4] = {};
  gemm256_core(A, Bm, row0, col0, lds, acc, tid);
#pragma unroll
  for (int nf = 0; nf < 4; nf++) {
    int col = col0 + wc * 64 + nf * 16 + l15;
    float bias = bo[col];
#pragma unroll
    for (int mf = 0; mf < 8; mf++) {
      int rowb = row0 + wr * 128 + mf * 16 + l4 * 4;
#pragma unroll
      for (int j = 0; j < 4; j++)
        out[(size_t)(rowb + j) * 1024 + col] = acc[mf][nf][j] + bias;
    }
  }
}

// ---------------- bias1[b,h,t,s] = sum_d q[b,h,t,d]*rel_k[h,idx[t,s],d] + T3
__global__ __launch_bounds__(256) void k_bias1(
    const u16* __restrict__ Qb, const u16* __restrict__ relq,
    const u16* __restrict__ relk, const int* __restrict__ relidx,
    u16* __restrict__ bias1) {
  const int tid = threadIdx.x, lane = tid & 63, w = tid >> 6;
  const int l15 = lane & 15, l4 = lane >> 4;
  const int t = blockIdx.x, h = blockIdx.y, bc = blockIdx.z;
  __shared__ char lds[16640];
  char* RK = lds;
  char* RQ = lds + 8192;
  float* T3 = (float*)(lds + 16384);
#pragma unroll
  for (int c = 0; c < 2; c++) {
    int ch = c * 256 + tid;
    int sr = ch >> 3, sl = (ch & 7) ^ (sr & 7);
    int ri = relidx[t * 64 + sr];
    size_t so = ((size_t)h * 225 + ri) * 64 + sl * 8;
    g2l16(relk + so, RK + c * 4096 + w * 1024);
    g2l16(relq + so, RQ + c * 4096 + w * 1024);
  }
  __syncthreads();
  if (tid < 64) {
    int sr = tid;
    float sum = 0.f;
#pragma unroll
    for (int sl = 0; sl < 8; sl++) {
      int o = sr * 128 + ((sl ^ (sr & 7)) << 4);
      bf16x8 aq = *(const bf16x8*)(RQ + o);
      bf16x8 ak = *(const bf16x8*)(RK + o);
#pragma unroll
      for (int j = 0; j < 8; j++) sum += (float)aq[j] * (float)ak[j];
    }
    T3[sr] = sum;
  }
  bf16x8 bfr[4][2];
#pragma unroll
  for (int n = 0; n < 4; n++)
#pragma unroll
    for (int kh = 0; kh < 2; kh++) {
      int r = n * 16 + l15;
      int sl = ((kh << 2) + l4) ^ (r & 7);
      bfr[n][kh] = *(const bf16x8*)(RK + r * 128 + sl * 16);
    }
  __syncthreads();
  f32x4 acc[4][4] = {};
#pragma unroll
  for (int m = 0; m < 4; m++) {
    int bb = bc * 256 + w * 64 + m * 16 + l15;
    const u16* ap = Qb + ((size_t)(bb * 16 + h)) * 4096 + t * 64 + l4 * 8;
    bf16x8 a0 = *(const bf16x8*)ap;
    bf16x8 a1 = *(const bf16x8*)(ap + 32);
#pragma unroll
    for (int n = 0; n < 4; n++) {
      acc[m][n] = MFMA16(a0, bfr[n][0], acc[m][n]);
      acc[m][n] = MFMA16(a1, bfr[n][1], acc[m][n]);
    }
  }
#pragma unroll
  for (int m = 0; m < 4; m++)
#pragma unroll
    for (int n = 0; n < 4; n++)
#pragma unroll
      for (int j = 0; j < 4; j++) {
        int bb = bc * 256 + w * 64 + m * 16 + l4 * 4 + j;
        int s_ = n * 16 + l15;
        bias1[((size_t)(bb * 16 + h)) * 4096 + t * 64 + s_] =
            f2bf(acc[m][n][j] + T3[s_]);
      }
}

// ---------------- bias2[b,h,s,t] = sum_d rel_q[h,idx[t,s],d]*k[b,h,s,d]
__global__ __launch_bounds__(256) void k_bias2(
    const u16* __restrict__ Kb, const u16* __restrict__ relq,
    const int* __restrict__ relidx, u16* __restrict__ bias2) {
  const int tid = threadIdx.x, lane = tid & 63, w = tid >> 6;
  const int l15 = lane & 15, l4 = lane >> 4;
  const int s = blockIdx.x, h = blockIdx.y, bc = blockIdx.z;
  __shared__ char lds[8192];
#pragma unroll
  for (int c = 0; c < 2; c++) {
    int ch = c * 256 + tid;
    int tq = ch >> 3, sl = (ch & 7) ^ (tq & 7);
    int ri = relidx[tq * 64 + s];
    g2l16(relq + ((size_t)h * 225 + ri) * 64 + sl * 8,
          lds + c * 4096 + w * 1024);
  }
  __syncthreads();
  bf16x8 bfr[4][2];
#pragma unroll
  for (int n = 0; n < 4; n++)
#pragma unroll
    for (int kh = 0; kh < 2; kh++) {
      int r = n * 16 + l15;
      int sl = ((kh << 2) + l4) ^ (r & 7);
      bfr[n][kh] = *(const bf16x8*)(lds + r * 128 + sl * 16);
    }
  f32x4 acc[4][4] = {};
#pragma unroll
  for (int m = 0; m < 4; m++) {
    int bb = bc * 256 + w * 64 + m * 16 + l15;
    const u16* ap = Kb + ((size_t)(bb * 16 + h)) * 4096 + s * 64 + l4 * 8;
    bf16x8 a0 = *(const bf16x8*)ap;
    bf16x8 a1 = *(const bf16x8*)(ap + 32);
#pragma unroll
    for (int n = 0; n < 4; n++) {
      acc[m][n] = MFMA16(a0, bfr[n][0], acc[m][n]);
      acc[m][n] = MFMA16(a1, bfr[n][1], acc[m][n]);
    }
  }
#pragma unroll
  for (int m = 0; m < 4; m++)
#pragma unroll
    for (int n = 0; n < 4; n++)
#pragma unroll
      for (int j = 0; j < 4; j++) {
        int bb = bc * 256 + w * 64 + m * 16 + l4 * 4 + j;
        int tcol = n * 16 + l15;
        bias2[((size_t)(bb * 16 + h)) * 4096 + s * 64 + tcol] =
            f2bf(acc[m][n][j]);
      }
}

// ---------------- attention per (b,h): S=QK^T + b1 + b2^T, softmax, P, PV ----
__global__ __launch_bounds__(256) void k_attn(
    const u16* __restrict__ Qb, const u16* __restrict__ Kb,
    const u16* __restrict__ Vb, const u16* __restrict__ b1g,
    const u16* __restrict__ b2g, u16* __restrict__ Pg,
    u16* __restrict__ aout) {
  const int tid = threadIdx.x, lane = tid & 63, w = tid >> 6;
  const int l15 = lane & 15, l4 = lane >> 4;
  const int b = blockIdx.x, h = blockIdx.y;
  __shared__ char lds[49152];
  char* Qt = lds;
  char* Kt = lds + 8192;
  char* Vt = lds + 16384;  // natural [s][d] layout now
  char* B1 = lds + 24576;
  char* B2 = lds + 32768;
  char* Pt = lds + 40960;
  const size_t base = ((size_t)(b * 16 + h)) * 4096;
#pragma unroll
  for (int c = 0; c < 2; c++) {
    int ch = c * 256 + tid;
    int r = ch >> 3, sl = (ch & 7) ^ (r & 7);
    size_t so = base + r * 64 + sl * 8;
    int dst = c * 4096 + w * 1024;
    g2l16(Qb + so, Qt + dst);
    g2l16(Kb + so, Kt + dst);
    g2l16(Vb + so, Vt + dst);
    g2l16(b1g + so, B1 + dst);
    g2l16(b2g + so, B2 + dst);
  }
  __syncthreads();
  // S = Q K^T, wave w owns rows [w*16, w*16+16)
  f32x4 acc[4] = {};
  bf16x8 qf[2];
  {
    int r = w * 16 + l15;
#pragma unroll
    for (int kh = 0; kh < 2; kh++) {
      int sl = ((kh << 2) + l4) ^ (r & 7);
      qf[kh] = *(const bf16x8*)(Qt + r * 128 + sl * 16);
    }
  }
#pragma unroll
  for (int n = 0; n < 4; n++) {
    int r = n * 16 + l15;
#pragma unroll
    for (int kh = 0; kh < 2; kh++) {
      int sl = ((kh << 2) + l4) ^ (r & 7);
      bf16x8 kf = *(const bf16x8*)(Kt + r * 128 + sl * 16);
      acc[n] = MFMA16(qf[kh], kf, acc[n]);
    }
  }
  const int t0 = w * 16 + l4 * 4;
#pragma unroll
  for (int j = 0; j < 4; j++) {
    int t_ = t0 + j;
    float lv[4];
#pragma unroll
    for (int n = 0; n < 4; n++) {
      int s_ = n * 16 + l15;
      float x = acc[n][j];
      x += bf2f(*(const u16*)(B1 + t_ * 128 + ((s_ * 2) ^ ((t_ & 7) << 4))));
      x += bf2f(*(const u16*)(B2 + s_ * 128 + ((t_ * 2) ^ ((s_ & 7) << 4))));
      lv[n] = x * 0.125f;
    }
    float mx = fmaxf(fmaxf(lv[0], lv[1]), fmaxf(lv[2], lv[3]));
#pragma unroll
    for (int d = 1; d < 16; d <<= 1) mx = fmaxf(mx, __shfl_xor(mx, d, 64));
    float e0 = __expf(lv[0] - mx), e1 = __expf(lv[1] - mx);
    float e2 = __expf(lv[2] - mx), e3 = __expf(lv[3] - mx);
    float sum = e0 + e1 + e2 + e3;
#pragma unroll
    for (int d = 1; d < 16; d <<= 1) sum += __shfl_xor(sum, d, 64);
    float inv = 1.0f / sum;
    float pe[4] = {e0 * inv, e1 * inv, e2 * inv, e3 * inv};
#pragma unroll
    for (int n = 0; n < 4; n++) {
      int s_ = n * 16 + l15;
      *(u16*)(Pt + t_ * 128 + ((s_ * 2) ^ ((t_ & 7) << 4))) = f2bf(pe[n]);
    }
  }
  __syncthreads();
  // P -> global (linearized, undo swizzle)
#pragma unroll
  for (int c = 0; c < 2; c++) {
    int ch = c * 256 + tid;
    int r = ch >> 3, sl = ch & 7;
    uint4 v = *(const uint4*)(Pt + r * 128 + ((sl ^ (r & 7)) << 4));
    *((uint4*)(Pg + base) + ch) = v;
  }
  // out_v = P * V; V is [s][d] -> B-frags via scalar column gather (k_relv
  // pattern, verified)
  f32x4 acc2[4] = {};
  bf16x8 pf[2];
  {
    int r = w * 16 + l15;
#pragma unroll
    for (int kh = 0; kh < 2; kh++) {
      int sl = ((kh << 2) + l4) ^ (r & 7);
      pf[kh] = *(const bf16x8*)(Pt + r * 128 + sl * 16);
    }
  }
#pragma unroll
  for (int n = 0; n < 4; n++) {
#pragma unroll
    for (int kh = 0; kh < 2; kh++) {
      bf16x8 tmp;
#pragma unroll
      for (int j = 0; j < 8; j++) {
        int s_ = (kh << 5) + (l4 << 3) + j;
        int d_ = n * 16 + l15;
        u16 uu = *(const u16*)(Vt + s_ * 128 + ((d_ * 2) ^ ((s_ & 7) << 4)));
        tmp[j] = __builtin_bit_cast(__bf16, uu);
      }
      acc2[n] = MFMA16(pf[kh], tmp, acc2[n]);
    }
  }
#pragma unroll
  for (int n = 0; n < 4; n++)
#pragma unroll
    for (int j = 0; j < 4; j++) {
      int t_ = t0 + j, d_ = n * 16 + l15;
      aout[((size_t)(b * 64 + t_)) * 1024 + h * 64 + d_] = f2bf(acc2[n][j]);
    }
}

// ---------------- out_relv: aout[b,t,h,d] += sum_s P[b,s]*rel_v[h,idx[t,s],d]
__global__ __launch_bounds__(256) void k_relv(
    const u16* __restrict__ Pg, const u16* __restrict__ relv,
    const int* __restrict__ relidx, u16* __restrict__ aout) {
  const int tid = threadIdx.x, lane = tid & 63, w = tid >> 6;
  const int l15 = lane & 15, l4 = lane >> 4;
  const int t = blockIdx.x, h = blockIdx.y, bc = blockIdx.z;
  __shared__ char lds[8192];
#pragma unroll
  for (int c = 0; c < 2; c++) {
    int ch = c * 256 + tid;
    int sr = ch >> 3, sl = (ch & 7) ^ (sr & 7);
    int ri = relidx[t * 64 + sr];
    g2l16(relv + ((size_t)h * 225 + ri) * 64 + sl * 8,
          lds + c * 4096 + w * 1024);
  }
  __syncthreads();
  bf16x8 bfr[4][2];
#pragma unroll
  for (int n = 0; n < 4; n++)
#pragma unroll
    for (int kh = 0; kh < 2; kh++) {
      bf16x8 tmp;
#pragma unroll
      for (int j = 0; j < 8; j++) {
        int s_ = (kh << 5) + (l4 << 3) + j;
        int d_ = n * 16 + l15;
        u16 u = *(const u16*)(lds + s_ * 128 + ((d_ * 2) ^ ((s_ & 7) << 4)));
        tmp[j] = __builtin_bit_cast(__bf16, u);
      }
      bfr[n][kh] = tmp;
    }
  f32x4 acc[4][4] = {};
#pragma unroll
  for (int m = 0; m < 4; m++) {
    int bb = bc * 256 + w * 64 + m * 16 + l15;
    const u16* ap = Pg + ((size_t)(bb * 16 + h)) * 4096 + t * 64 + l4 * 8;
    bf16x8 a0 = *(const bf16x8*)ap;
    bf16x8 a1 = *(const bf16x8*)(ap + 32);
#pragma unroll
    for (int n = 0; n < 4; n++) {
      acc[m][n] = MFMA16(a0, bfr[n][0], acc[m][n]);
      acc[m][n] = MFMA16(a1, bfr[n][1], acc[m][n]);
    }
  }
#pragma unroll
  for (int m = 0; m < 4; m++)
#pragma unroll
    for (int n = 0; n < 4; n++)
#pragma unroll
      for (int j = 0; j < 4; j++) {
        int bb = bc * 256 + w * 64 + m * 16 + l4 * 4 + j;
        int d_ = n * 16 + l15;
        size_t o = ((size_t)(bb * 64 + t)) * 1024 + h * 64 + d_;
        aout[o] = f2bf(bf2f(aout[o]) + acc[m][n][j]);
      }
}

extern "C" void kernel_launch(void* const* d_in, const int* in_sizes, int n_in,
                              void* d_out, int out_size, void* d_ws,
                              size_t ws_size, hipStream_t stream) {
  const float* x = (const float*)d_in[0];
  const float* Wq = (const float*)d_in[1];
  const float* bq = (const float*)d_in[2];
  const float* Wk = (const float*)d_in[3];
  const float* bk = (const float*)d_in[4];
  const float* Wv = (const float*)d_in[5];
  const float* bv = (const float*)d_in[6];
  const float* Wo = (const float*)d_in[7];
  const float* bo = (const float*)d_in[8];
  const float* rq = (const float*)d_in[9];
  const float* rk = (const float*)d_in[10];
  const float* rv = (const float*)d_in[11];
  const int* ridx = (const int*)d_in[12];
  float* out = (float*)d_out;

  char* ws = (char*)d_ws;
  const size_t MB = 1ull << 20;
  u16* xb = (u16*)(ws + 0);  // reused as P after k_gemm_qkv consumes it
  u16* Qb = (u16*)(ws + 64 * MB);
  u16* Kb = (u16*)(ws + 128 * MB);
  u16* Vb = (u16*)(ws + 192 * MB);
  u16* b1 = (u16*)(ws + 256 * MB);
  u16* b2 = (u16*)(ws + 320 * MB);
  u16* aout = (u16*)(ws + 384 * MB);
  u16* wqkv = (u16*)(ws + 448 * MB);
  u16* wo = (u16*)(ws + 454 * MB);
  u16* relq = (u16*)(ws + 456 * MB);
  u16* relk = (u16*)(ws + 457 * MB);
  u16* relv = (u16*)(ws + 458 * MB);
  u16* Pg = xb;

  k_cvt<<<32768, 256, 0, stream>>>(x, xb, 8388608);
  k_cvt<<<1024, 256, 0, stream>>>(Wq, wqkv, 262144);
  k_cvt<<<1024, 256, 0, stream>>>(Wk, wqkv + 1048576, 262144);
  k_cvt<<<1024, 256, 0, stream>>>(Wv, wqkv + 2097152, 262144);
  k_cvt<<<1024, 256, 0, stream>>>(Wo, wo, 262144);
  k_cvt<<<225, 256, 0, stream>>>(rq, relq, 57600);
  k_cvt<<<225, 256, 0, stream>>>(rk, relk, 57600);
  k_cvt<<<225, 256, 0, stream>>>(rv, relv, 57600);

  k_gemm_qkv<<<1536, 512, 0, stream>>>(xb, wqkv, bq, bk, bv, Qb, Kb, Vb);
  k_bias1<<<dim3(64, 16, 2), 256, 0, stream>>>(Qb, relq, relk, ridx, b1);
  k_bias2<<<dim3(64, 16, 2), 256, 0, stream>>>(Kb, relq, ridx, b2);
  k_attn<<<dim3(512, 16), 256, 0, stream>>>(Qb, Kb, Vb, b1, b2, Pg, aout);
  k_relv<<<dim3(64, 16, 2), 256, 0, stream>>>(Pg, relv, ridx, aout);
  k_gemm_out<<<512, 512, 0, stream>>>(aout, wo, bo, out);
}